// Round 5
// baseline (248.684 us; speedup 1.0000x reference)
//
#include <hip/hip_runtime.h>
#include <hip/hip_fp16.h>
#include <hip/hip_bf16.h>
#include <stdint.h>

// Problem constants
#define LSEQ 524288   // sequence length
// S = I = C = 64, O = 32

// Phase A (PDA probs via 3-history factored tables): 8192 waves x 64 t's, no recurrence
#define KA 64
#define GA2 (LSEQ / KA / 4)   // 2048 blocks x 256 thr (4 waves/block)

// Phase B (counter scan + readout): 2048 chunks x 256 steps, 2560-step burn-in
#define KB 256
#define WB 2560
#define GB (LSEQ / KB)   // 2048 blocks (64 thr each) -> 8 blocks/CU, 2 waves/SIMD

// Workspace layout (bytes). Total ~4.76 MB.
#define WS_ST   0u        // ushort[64*64*64]: staged softmax(T) fp16, [s][i][j]  (512KB)
#define WS_WB   524288u   // ushort[32*64]: out_W as bf16, row-major [O][C]       (4KB)
#define WS_X3   528384u   // uint32[3]: exact probs for t=0..2, packed (inc,dec) f16
#define WS_IT   528416u   // float2[64*64]: ITD[d][j] = (inc_raw[j,d], dec_raw[j,d]) (32KB)
#define WS_V    561184u   // uint32[64*64*64]: V[a*64+b][s'] = f16(m_a . T_b), DUP lo/hi (1MB)
#define WS_G    1609760u  // uint32[64*64*64]: G[c*64+d][s'] = pack(f16(T_c.inc[:,d]), f16(T_c.dec[:,d])) (1MB)
#define WS_PP   2658336u  // uint32[LSEQ]: packed (inc_p, dec_p) f16 pairs        (2MB)

typedef __attribute__((ext_vector_type(2))) __fp16 fp16x2;   // native type of cvt_pkrtz
typedef __attribute__((ext_vector_type(8))) short short8;
typedef __attribute__((ext_vector_type(4))) float f32x4;

// ---- DPP controls (gfx9/CDNA encodings)
#define DPP_ROW_ROR1   0x121
#define DPP_ROW_ROR2   0x122
#define DPP_ROW_ROR4   0x124
#define DPP_ROW_ROR8   0x128
#define DPP_WAVE_SHL1  0x130  // dst[i] = src[i+1], lane63 invalid (bound_ctrl -> 0)
#define DPP_WAVE_ROR1  0x13C  // dst[i] = src[(i-1)&63]
#define DPP_BCAST15    0x142
#define DPP_BCAST31    0x143

template<int CTRL, bool BC>
static __device__ __forceinline__ int dpp_mov_i(int x) {
    return __builtin_amdgcn_update_dpp(0, x, CTRL, 0xF, 0xF, BC);
}
template<int CTRL>
static __device__ __forceinline__ float dpp_mov_f(float x) {
    return __int_as_float(__builtin_amdgcn_update_dpp(0, __float_as_int(x), CTRL, 0xF, 0xF, false));
}
template<int CTRL>
static __device__ __forceinline__ float dpp_mov_f_bc(float x) {
    return __int_as_float(__builtin_amdgcn_update_dpp(0, __float_as_int(x), CTRL, 0xF, 0xF, true));
}
static __device__ __forceinline__ uint32_t h2bits(__half2 h) {
    uint32_t u; __builtin_memcpy(&u, &h, 4); return u;
}
static __device__ __forceinline__ __half2 bits2h(uint32_t u) {
    __half2 h; __builtin_memcpy(&h, &u, 4); return h;
}
static __device__ __forceinline__ uint32_t h2add(uint32_t a, uint32_t b) {
    return h2bits(__hadd2(bits2h(a), bits2h(b)));
}
static __device__ __forceinline__ float rcp_fast(float x) {
#if __has_builtin(__builtin_amdgcn_rcpf)
    return __builtin_amdgcn_rcpf(x);
#else
    return 1.0f / x;
#endif
}
static __device__ __forceinline__ unsigned short f2bf(float x) {
    __hip_bfloat16 b = __float2bfloat16(x);
    unsigned short u; __builtin_memcpy(&u, &b, 2);
    return u;
}
static __device__ __forceinline__ float bcast_lane_f(float v, int lane) {
    return __int_as_float(__builtin_amdgcn_readlane(__float_as_int(v), lane));
}
// full-wave sum of packed fp16 pair: row_ror allreduce + bcast15/31; broadcast from lane 63
static __device__ __forceinline__ uint32_t wave_red_sum_h2(uint32_t v) {
    v = h2add(v, (uint32_t)dpp_mov_i<DPP_ROW_ROR8, false>((int)v));
    v = h2add(v, (uint32_t)dpp_mov_i<DPP_ROW_ROR4, false>((int)v));
    v = h2add(v, (uint32_t)dpp_mov_i<DPP_ROW_ROR2, false>((int)v));
    v = h2add(v, (uint32_t)dpp_mov_i<DPP_ROW_ROR1, false>((int)v));
    v = h2add(v, (uint32_t)dpp_mov_i<DPP_BCAST15, false>((int)v));
    v = h2add(v, (uint32_t)dpp_mov_i<DPP_BCAST31, false>((int)v));
    return (uint32_t)__builtin_amdgcn_readlane((int)v, 63);
}
// 16-lane-group allreduce via row rotations (counter epilogue softmax)
static __device__ __forceinline__ float grp16_max(float v) {
    v = fmaxf(v, dpp_mov_f<DPP_ROW_ROR8>(v));
    v = fmaxf(v, dpp_mov_f<DPP_ROW_ROR4>(v));
    v = fmaxf(v, dpp_mov_f<DPP_ROW_ROR2>(v));
    v = fmaxf(v, dpp_mov_f<DPP_ROW_ROR1>(v));
    return v;
}
static __device__ __forceinline__ float grp16_sum(float v) {
    v += dpp_mov_f<DPP_ROW_ROR8>(v);
    v += dpp_mov_f<DPP_ROW_ROR4>(v);
    v += dpp_mov_f<DPP_ROW_ROR2>(v);
    v += dpp_mov_f<DPP_ROW_ROR1>(v);
    return v;
}
static __device__ __forceinline__ uint32_t pack_pair(float a, float b) {
    fp16x2 p = __builtin_amdgcn_cvt_pkrtz(a, b);
    uint32_t u; __builtin_memcpy(&u, &p, 4);
    return u;
}
static __device__ __forceinline__ float lo16f(uint32_t u) {
    return __half2float(__ushort_as_half((unsigned short)(u & 0xFFFFu)));
}
static __device__ __forceinline__ float hi16f(uint32_t u) {
    return __half2float(__ushort_as_half((unsigned short)(u >> 16)));
}
static __device__ __forceinline__ float half_at(const short8& v, int idx) {
    return __half2float(__ushort_as_half((unsigned short)v[idx]));
}

// ---------------- prep stage 1: softmax rows of T (coalesced) + W + incdec transpose ----------------
__global__ __launch_bounds__(64) void prep_kernel(
    const float* __restrict__ T_raw, const float* __restrict__ out_W,
    const float* __restrict__ inc_raw, const float* __restrict__ dec_raw,
    uint8_t* __restrict__ ws)
{
    int lane = threadIdx.x;
    int bid = blockIdx.x;
    if (bid < 4096) {
        // one wave per (s,i) row: softmax over j, store fp16 coalesced to staged [s][i][j]
        float x = T_raw[bid * 64 + lane];
        float m = x;
        #pragma unroll
        for (int off = 32; off; off >>= 1) m = fmaxf(m, __shfl_xor(m, off));
        float e = __expf(x - m);
        float sum = e;
        #pragma unroll
        for (int off = 32; off; off >>= 1) sum += __shfl_xor(sum, off);
        float v = e / sum;
        ((unsigned short*)(ws + WS_ST))[bid * 64 + lane] = __half_as_ushort(__float2half(v));
    } else if (bid == 4096) {
        unsigned short* wbp = (unsigned short*)(ws + WS_WB);
        #pragma unroll
        for (int r = 0; r < 32; ++r) {
            int idx = r * 64 + lane;
            wbp[idx] = f2bf(out_W[idx]);
        }
    } else {
        // ITD[d][j] = (inc_raw[j,d], dec_raw[j,d]); lane = d, coalesced reads over lanes
        float2* itd = (float2*)(ws + WS_IT);
        for (int j = 0; j < 64; ++j) {
            float2 v;
            v.x = inc_raw[j * 64 + lane];
            v.y = dec_raw[j * 64 + lane];
            itd[lane * 64 + j] = v;
        }
    }
}

// ---------------- prep stage 2 (fused): V + G tables + exact probs for t<3 ----------------
// blocks 0..4095 (a,b):   V[a,b][s'] = sum_s m_a[s]*T[s,b,s'], m_a computed inline (readlane bcast)
// blocks 4096..8191 (c,d): G[c,d][s'] = pack(f16(sum_j T[s',c,j]*inc[j,d]), f16(...dec...))
// block 8192: exact 3-step PDA replay from softmax(init); writes X3 packed probs.
__global__ __launch_bounds__(64) void prepVG_kernel(
    const int* __restrict__ seq, const float* __restrict__ inc_raw,
    const float* __restrict__ dec_raw, const float* __restrict__ initv,
    uint8_t* __restrict__ ws)
{
    __shared__ float lsd[64];
    int lane = threadIdx.x;
    int bid = blockIdx.x;
    const unsigned short* st = (const unsigned short*)(ws + WS_ST);
    if (bid < 4096) {
        int a = bid >> 6, b = bid & 63;
        // m_a[lane] = mean_s T[s,a,lane]  (64 coalesced 128B loads)
        float acc = 0.f;
        #pragma unroll 8
        for (int s = 0; s < 64; ++s)
            acc += __half2float(__ushort_as_half(st[s * 4096 + a * 64 + lane]));
        float mreg = acc * (1.0f / 64.0f);
        // V[a,b][lane] = sum_s m_a[s] * T[s,b,lane]  (m_a[s] via literal readlane)
        float vacc = 0.f;
        #pragma unroll
        for (int s = 0; s < 64; ++s)
            vacc = fmaf(bcast_lane_f(mreg, s),
                        __half2float(__ushort_as_half(st[s * 4096 + b * 64 + lane])), vacc);
        uint32_t hv = (uint32_t)__half_as_ushort(__float2half(vacc));
        ((uint32_t*)(ws + WS_V))[bid * 64 + lane] = hv | (hv << 16);
    } else if (bid < 8192) {
        int cd = bid - 4096;
        int c = cd >> 6, d = cd & 63;
        const unsigned short* trow = st + lane * 4096 + c * 64;   // 64 halves, contiguous per lane
        short8 tr[8];
        #pragma unroll
        for (int w = 0; w < 8; ++w) tr[w] = *(const short8*)(trow + w * 8);
        const float2* itd = (const float2*)(ws + WS_IT) + d * 64;  // uniform -> s_load_dwordx2
        float gi = 0.f, gd = 0.f;
        #pragma unroll
        for (int j = 0; j < 64; ++j) {
            float tv = half_at(tr[j >> 3], j & 7);
            float2 p = itd[j];
            gi = fmaf(tv, p.x, gi);
            gd = fmaf(tv, p.y, gd);
        }
        ((uint32_t*)(ws + WS_G))[cd * 64 + lane] = pack_pair(gi, gd);
    } else {
        // exact 3 steps: s0 = softmax(init)
        float x = initv[lane];
        float m = x;
        #pragma unroll
        for (int off = 32; off; off >>= 1) m = fmaxf(m, __shfl_xor(m, off));
        float e = __expf(x - m);
        float ssum = e;
        #pragma unroll
        for (int off = 32; off; off >>= 1) ssum += __shfl_xor(ssum, off);
        float sv = e / ssum;
        uint32_t* x3 = (uint32_t*)(ws + WS_X3);
        for (int t = 0; t < 3; ++t) {
            int it = seq[t];
            float li = inc_raw[lane * 64 + it] * sv;
            float ld = dec_raw[lane * 64 + it] * sv;
            #pragma unroll
            for (int off = 32; off; off >>= 1) { li += __shfl_xor(li, off); ld += __shfl_xor(ld, off); }
            float e0 = __expf(li), e1 = __expf(ld);
            float rs = rcp_fast(e0 + e1 + 1.0f);
            if (lane == 0) x3[t] = pack_pair(e0 * rs, e1 * rs);
            // state update: new[j] = sum_s sv[s] * T[s,it,j]
            lsd[lane] = sv;
            __syncthreads();
            float ns = 0.f;
            #pragma unroll 8
            for (int s2 = 0; s2 < 64; ++s2)
                ns = fmaf(lsd[s2],
                          __half2float(__ushort_as_half(st[s2 * 4096 + it * 64 + lane])), ns);
            __syncthreads();
            sv = ns;
        }
    }
}

// ---------------- phase A: probs via factored 3-history tables (NO recurrence) ----------------
// lambda_inc(t) = V[i_{t-3},i_{t-2}] . G_inc[i_{t-1},i_t]  (exact for t>=3 up to ||(s-u)Delta^3|| ~ 1e-7)
// Per t: 2 dword gathers (L2-resident 2MB tables) + packed-f16 wave reduce. Fully parallel over t.
// KA=64 -> 8192 waves (8/SIMD): latency hidden by TLP.
__global__ __launch_bounds__(256) void pda_kernel(
    const int* __restrict__ seq, uint8_t* __restrict__ ws)
{
    int lane = threadIdx.x & 63;
    int g = __builtin_amdgcn_readfirstlane(blockIdx.x * 4 + (threadIdx.x >> 6));
    const uint32_t* Vp = (const uint32_t*)(ws + WS_V);
    const uint32_t* Gp = (const uint32_t*)(ws + WS_G);
    uint32_t* pp = (uint32_t*)(ws + WS_PP);
    const uint32_t* x3 = (const uint32_t*)(ws + WS_X3);

    int t0w = g * KA;
    // rolling scalar history (clamped below 0; t=0..2 overwritten with exact values)
    int a = seq[t0w >= 3 ? t0w - 3 : 0];
    int b = seq[t0w >= 2 ? t0w - 2 : 0];
    int c = seq[t0w >= 1 ? t0w - 1 : 0];
    int d = seq[t0w];
    uint32_t pkK = 0;
    #pragma unroll 4
    for (int loc = 0; loc < KA; ++loc) {
        int ab = a * 64 + b, cd = c * 64 + d;
        uint32_t vv = Vp[ab * 64 + lane];
        uint32_t gg = Gp[cd * 64 + lane];
        uint32_t prod = h2bits(__hmul2(bits2h(vv), bits2h(gg)));
        uint32_t tot = wave_red_sum_h2(prod);
        float inc_l = lo16f(tot);
        float dec_l = hi16f(tot);
        // softmax over {inc_l, dec_l, 0}: logits tiny, skip max-shift
        float e0 = __expf(inc_l);
        float e1 = __expf(dec_l);
        float rs = rcp_fast(e0 + e1 + 1.0f);
        uint32_t pk = pack_pair(e0 * rs, e1 * rs);
        if (lane == loc) pkK = pk;
        a = b; b = c; c = d;
        int ni = t0w + loc + 1;
        d = seq[ni < LSEQ ? ni : LSEQ - 1];
    }
    pp[t0w + lane] = pkK;                          // coalesced flush, one store per wave
    if (g == 0 && lane < 3) pp[lane] = x3[lane];   // exact t=0..2 (same wave; ordered)
}

// ---------------- phase B: counter scan + batched MFMA readout ----------------
// KB=256 -> 2048 blocks = 2 waves/SIMD: second wave fills chain stalls/hazard nops.
// Probs: one coalesced vector load per 64-step batch (double-buffered), staged to LDS,
// per-step ds_read_b32 broadcast (induction addresses -> compiler hoists; off the dist chain).
// Chain: dist' = fma(dec, fma(m1n,dist,dn), fma(inc, up-dist, dist)); up=wave_ror1, dn=wave_shl1(bc0).
__global__ __launch_bounds__(64) void counter_kernel(
    const float* __restrict__ out_b, float* __restrict__ out,
    uint8_t* __restrict__ ws)
{
    __shared__ unsigned short stage[64 * 72];   // 64 staged dist rows, stride 72 halves
    __shared__ uint32_t ppl[2][64];             // double-buffered packed probs
    int lane = threadIdx.x;
    int g = blockIdx.x;
    const uint32_t* __restrict__ ppArr = (const uint32_t*)(ws + WS_PP);
    const unsigned short* wbp = (const unsigned short*)(ws + WS_WB);

    int t0 = g * KB;
    bool exact = (t0 <= WB);          // early chunks replay exactly from t=0 (one-hot init)
    int warm = exact ? t0 : WB;       // multiple of 64
    int tstart = t0 - warm;
    int nb  = (warm + KB) >> 6;       // total 64-step batches
    int nwb = warm >> 6;              // warm batches

    float dist = exact ? (lane == 0 ? 1.0f : 0.0f) : (1.0f / 64.0f);
    float m1n = (lane == 0) ? 0.0f : -1.0f;   // -(lane!=0), constant

    int q = lane >> 4, c16 = lane & 15;
    // B-operand frags: lane holds W[n = nt*16 + c16][k = kb*32 + q*8 + j]
    short8 wf00, wf01, wf10, wf11;
    {
        int n0 = c16, n1 = 16 + c16;
        int kk = q * 8;
        wf00 = *(const short8*)(wbp + n0 * 64 + kk);
        wf10 = *(const short8*)(wbp + n0 * 64 + 32 + kk);
        wf01 = *(const short8*)(wbp + n1 * 64 + kk);
        wf11 = *(const short8*)(wbp + n1 * 64 + 32 + kk);
    }
    float b0 = out_b[c16], b1 = out_b[16 + c16];

    uint32_t pv = ppArr[tstart + lane];   // batch 0 (coalesced, 64 steps per load)

    for (int b = 0; b < nb; ++b) {
        ppl[b & 1][lane] = pv;
        if (b + 1 < nb) pv = ppArr[tstart + (b + 1) * 64 + lane];   // prefetch next batch
        const uint32_t* pb = ppl[b & 1];
        if (b < nwb) {
            // warm: recurrence only
            #pragma unroll
            for (int j = 0; j < 64; ++j) {
                uint32_t ppv = pb[j];              // uniform ds_read broadcast, off-chain
                float inc = lo16f(ppv);
                float dec = hi16f(ppv);
                float up = dpp_mov_f<DPP_WAVE_ROR1>(dist);
                float dn = dpp_mov_f_bc<DPP_WAVE_SHL1>(dist);
                float t2 = fmaf(m1n, dist, dn);
                dist = fmaf(dec, t2, fmaf(inc, up - dist, dist));
            }
        } else {
            int eb = b - nwb;
            #pragma unroll
            for (int j = 0; j < 64; ++j) {
                stage[j * 72 + lane] = f2bf(dist);      // PRE-update dist row
                uint32_t ppv = pb[j];
                float inc = lo16f(ppv);
                float dec = hi16f(ppv);
                float up = dpp_mov_f<DPP_WAVE_ROR1>(dist);
                float dn = dpp_mov_f_bc<DPP_WAVE_SHL1>(dist);
                float t2 = fmaf(m1n, dist, dn);
                dist = fmaf(dec, t2, fmaf(inc, up - dist, dist));
            }
            int rowbase0 = t0 + eb * 64;
            #pragma unroll
            for (int t = 0; t < 4; ++t) {
                // same-wave LDS ordering: staging writes complete before these reads
                const unsigned short* sp = stage + (t * 16 + c16) * 72;
                short8 a0 = *(const short8*)(sp + q * 8);        // k 0..31
                short8 a1 = *(const short8*)(sp + 32 + q * 8);   // k 32..63
                f32x4 d0 = {0.f, 0.f, 0.f, 0.f};
                f32x4 d1 = {0.f, 0.f, 0.f, 0.f};
                d0 = __builtin_amdgcn_mfma_f32_16x16x32_bf16(a0, wf00, d0, 0, 0, 0);
                d0 = __builtin_amdgcn_mfma_f32_16x16x32_bf16(a1, wf10, d0, 0, 0, 0);
                d1 = __builtin_amdgcn_mfma_f32_16x16x32_bf16(a0, wf01, d1, 0, 0, 0);
                d1 = __builtin_amdgcn_mfma_f32_16x16x32_bf16(a1, wf11, d1, 0, 0, 0);
                int rowbase = rowbase0 + t * 16;
                // C/D: col = lane&15, row = q*4 + r -> softmax over 32 outputs per row
                #pragma unroll
                for (int r = 0; r < 4; ++r) {
                    float l0 = d0[r] + b0, l1 = d1[r] + b1;
                    float mm = grp16_max(fmaxf(l0, l1));
                    float e0 = __expf(l0 - mm), e1 = __expf(l1 - mm);
                    float ss = grp16_sum(e0 + e1);
                    float rinv = rcp_fast(ss);
                    int row = rowbase + q * 4 + r;
                    out[row * 32 + c16]      = e0 * rinv;
                    out[row * 32 + 16 + c16] = e1 * rinv;
                }
            }
        }
    }
}

extern "C" void kernel_launch(void* const* d_in, const int* in_sizes, int n_in,
                              void* d_out, int out_size, void* d_ws, size_t ws_size,
                              hipStream_t stream) {
    const int*   seq     = (const int*)d_in[0];
    const float* T_raw   = (const float*)d_in[1];
    const float* inc_raw = (const float*)d_in[2];
    const float* dec_raw = (const float*)d_in[3];
    const float* out_W   = (const float*)d_in[4];
    const float* out_b   = (const float*)d_in[5];
    const float* initv   = (const float*)d_in[6];
    float* out = (float*)d_out;
    uint8_t* ws = (uint8_t*)d_ws;
    (void)in_sizes; (void)n_in; (void)out_size; (void)ws_size;

    hipLaunchKernelGGL(prep_kernel,  dim3(4098), dim3(64), 0, stream,
                       T_raw, out_W, inc_raw, dec_raw, ws);
    hipLaunchKernelGGL(prepVG_kernel, dim3(8193), dim3(64), 0, stream,
                       seq, inc_raw, dec_raw, initv, ws);
    hipLaunchKernelGGL(pda_kernel,   dim3(GA2), dim3(256), 0, stream, seq, ws);
    hipLaunchKernelGGL(counter_kernel, dim3(GB), dim3(64), 0, stream, out_b, out, ws);
}